// Round 4
// baseline (263.184 us; speedup 1.0000x reference)
//
#include <hip/hip_runtime.h>
#include <math.h>

#define DIM     4096
#define NEXP    64
#define TOPK_N  8
#define TAU     2.0e-4f
#define TB      16                 // tokens per block
#define BK      512                // k per staged A-tile (2 KB contiguous per row)
#define KT      (DIM / BK)         // 8 k-tiles
#define K32     4                  // k32 MFMA steps per wave per tile (BK/4 waves/32)

#define WS_WHI_OFF  0
#define WS_WLO_OFF  524288

typedef __attribute__((ext_vector_type(8))) short short8;   // 8 bf16
typedef __attribute__((ext_vector_type(4))) float f32x4;

// fp32 -> bf16 hi (trunc) + bf16 lo (trunc of exact residual)
__device__ __forceinline__ void cvt8(float4 a0, float4 a1, short8& hv, short8& lv) {
    float f[8] = {a0.x, a0.y, a0.z, a0.w, a1.x, a1.y, a1.z, a1.w};
    union { short8 v; unsigned u[4]; } H, L;
    #pragma unroll
    for (int i = 0; i < 4; ++i) {
        unsigned b0 = __float_as_uint(f[2*i]);
        unsigned b1 = __float_as_uint(f[2*i+1]);
        float r0 = f[2*i]   - __uint_as_float(b0 & 0xffff0000u);
        float r1 = f[2*i+1] - __uint_as_float(b1 & 0xffff0000u);
        H.u[i] = (b0 >> 16) | (b1 & 0xffff0000u);
        L.u[i] = (__float_as_uint(r0) >> 16) | (__float_as_uint(r1) & 0xffff0000u);
    }
    hv = H.v; lv = L.v;
}

// async global->LDS, 16B per lane; LDS dest = base + lane*16 (linear)
__device__ __forceinline__ void async16(void* lds, const void* g) {
    __builtin_amdgcn_global_load_lds(
        (const __attribute__((address_space(1))) unsigned int*)g,
        (__attribute__((address_space(3))) unsigned int*)lds, 16, 0, 0);
}

// ---------------- Pass 0: w fp32 -> bf16 hi/lo ----------------
__global__ __launch_bounds__(256, 4)
void cvt_w_kernel(const float* __restrict__ w, unsigned short* __restrict__ whi,
                  unsigned short* __restrict__ wlo) {
    const int g = blockIdx.x * 256 + threadIdx.x;
    const float* p = w + (size_t)g * 8;
    union { short8 v; uint4 q; } H, L;
    float4 a0 = *(const float4*)(p);
    float4 a1 = *(const float4*)(p + 4);
    cvt8(a0, a1, H.v, L.v);
    *(uint4*)(whi + (size_t)g * 8) = H.q;
    *(uint4*)(wlo + (size_t)g * 8) = L.q;
}

// ---------------- Pass 1: row-contiguous-staged MFMA GEMM + softmax + top-8 + recheck ----
// block = 512 thr = 8 waves, TB=16 tokens x 64 experts, KT=8 tiles of BK=512.
// HBM-efficiency fix: each A(x) row k-slice is staged as 2x1KB CONTIGUOUS global_load_lds
// (2 KB sequential runs per row ~ HBM page) instead of 128-512B scattered granules.
// B (1 MB, shared, L2-resident) is NOT staged: per-lane short8 loads inside compute.
// LDS 64KB A double-buffer -> 2 blocks/CU for cross-block barrier overlap.
// Wave wv: k-128-substep ss=wv&3 within tile, expert-half hf=wv>>2.
__global__ __launch_bounds__(512, 2)
void gemm_kernel(const float* __restrict__ x, const unsigned short* __restrict__ whi,
                 const unsigned short* __restrict__ wlo, const float* __restrict__ bias,
                 const float* __restrict__ wfp, float* __restrict__ out, int ntok) {
    __shared__ struct {
        union {
            float A[2][TB][BK];       // 64 KB (rows 2 KB, linear)
            float part[4][TB][65];    // 16.6 KB (epilogue overlay)
        } u;
        float  s[TB][68];
        float  top9[TB][9];
        double dsc[NEXP];
        int    nflag;
        int    ftok[TB];
        float  fninth[TB];
    } sm;

    const int tid  = threadIdx.x;
    const int lane = tid & 63;
    const int wv   = tid >> 6;
    const int nl   = lane & 15;
    const int q    = lane >> 4;
    const int tok0 = blockIdx.x * TB;
    if (tid == 0) sm.nflag = 0;

    const int ss = wv & 3;          // k-128 substep within BK tile
    const int hf = wv >> 2;         // expert half

    // A staging: 4 gll insts per wave per tile; inst i -> row wv*2+(i>>1), half i&1.
    // Source pre-XOR'd with the row swizzle (both-sides involution, rule 21).
    int arow[4], ahalf[4];
    const float* gA[4];
    #pragma unroll
    for (int i = 0; i < 4; ++i) {
        arow[i]  = wv * 2 + (i >> 1);
        ahalf[i] = i & 1;
        const int lb = ((lane * 16) ^ ((arow[i] & 7) << 4)) >> 2;  // swizzled float off in 1KB half
        gA[i] = x + (size_t)(tok0 + arow[i]) * DIM + ahalf[i] * 256 + lb;
    }

    // B per-lane row bases (expert rows, 16KB stride scattered -> L2 hits)
    size_t boffB[2];
    #pragma unroll
    for (int nf = 0; nf < 2; ++nf) boffB[nf] = (size_t)((hf * 2 + nf) * 16 + nl) * DIM;

    f32x4 acc[2];
    acc[0] = (f32x4){0.f, 0.f, 0.f, 0.f};
    acc[1] = (f32x4){0.f, 0.f, 0.f, 0.f};

#define STAGE(b_, kf_) do {                                                    \
        _Pragma("unroll")                                                      \
        for (int i_ = 0; i_ < 4; ++i_)                                         \
            async16(&sm.u.A[b_][arow[i_]][ahalf[i_] * 256], gA[i_] + (kf_));   \
    } while (0)

#define COMPUTE(b_, kf_) do {                                                  \
        const char* rowp_ = (const char*)&sm.u.A[b_][nl][0];                   \
        const int sw_ = (nl & 7) << 4;                                         \
        _Pragma("unroll")                                                      \
        for (int ks_ = 0; ks_ < K32; ++ks_) {                                  \
            const int base_ = ss * 512 + ks_ * 128 + q * 32;                   \
            float4 a0_ = *(const float4*)(rowp_ + (base_ ^ sw_));              \
            float4 a1_ = *(const float4*)(rowp_ + ((base_ + 16) ^ sw_));       \
            short8 ahi_, alo_;                                                 \
            cvt8(a0_, a1_, ahi_, alo_);                                        \
            const int kg_ = (kf_) + ss * 128 + ks_ * 32 + q * 8;               \
            _Pragma("unroll")                                                  \
            for (int nf_ = 0; nf_ < 2; ++nf_) {                                \
                short8 bh_ = *(const short8*)(whi + boffB[nf_] + kg_);         \
                short8 bl_ = *(const short8*)(wlo + boffB[nf_] + kg_);         \
                acc[nf_] = __builtin_amdgcn_mfma_f32_16x16x32_bf16(ahi_, bl_, acc[nf_], 0, 0, 0); \
                acc[nf_] = __builtin_amdgcn_mfma_f32_16x16x32_bf16(alo_, bh_, acc[nf_], 0, 0, 0); \
                acc[nf_] = __builtin_amdgcn_mfma_f32_16x16x32_bf16(ahi_, bh_, acc[nf_], 0, 0, 0); \
            }                                                                  \
        }                                                                      \
    } while (0)

    // prologue: fill buffer 0
    STAGE(0, 0);
    __syncthreads();
    #pragma unroll 2
    for (int kt = 0; kt < KT; ++kt) {
        const int b = kt & 1;
        if (kt + 1 < KT) STAGE(b ^ 1, (kt + 1) * BK);   // fire-and-forget next tile
        __builtin_amdgcn_sched_barrier(0);              // keep issue before compute
        COMPUTE(b, kt * BK);
        __syncthreads();                                // drain overlaps other block on CU
    }

#undef STAGE
#undef COMPUTE

    // split-K partials -> LDS overlay (safe: last barrier ended all staging reads)
    #pragma unroll
    for (int nf = 0; nf < 2; ++nf)
        #pragma unroll
        for (int r = 0; r < 4; ++r)
            sm.u.part[ss][q * 4 + r][(hf * 2 + nf) * 16 + nl] = acc[nf][r];
    __syncthreads();

    // reduce 4 partials (fixed order), add bias: 1024 values / 512 threads
    #pragma unroll
    for (int i = 0; i < (TB * NEXP) / 512; ++i) {
        const int p  = tid + i * 512;
        const int tk = p >> 6, e = p & 63;
        float s = sm.u.part[0][tk][e];
        #pragma unroll
        for (int k = 1; k < 4; ++k) s += sm.u.part[k][tk][e];
        sm.s[tk][e] = s + bias[e];
    }
    __syncthreads();

    // softmax + parallel-rank top-k: wave wv -> tokens wv*2..+2, lane = expert
    float* __restrict__ out_idx = out + (size_t)ntok * NEXP;
    #pragma unroll
    for (int t = 0; t < 2; ++t) {
        const int tokl = wv * 2 + t;
        const int tok  = tok0 + tokl;
        const float s  = sm.s[tokl][lane];

        float m = s;
        #pragma unroll
        for (int off = 32; off > 0; off >>= 1)
            m = fmaxf(m, __shfl_xor(m, off, 64));
        const float ex = expf(s - m);
        float sum = ex;
        #pragma unroll
        for (int off = 32; off > 0; off >>= 1)
            sum += __shfl_xor(sum, off, 64);
        out[(size_t)tok * NEXP + lane] = ex / sum;

        // rank = #{j : v_j > s || (v_j == s && j < lane)}
        int rank = 0;
        #pragma unroll
        for (int i = 0; i < 16; ++i) {
            const float4 v4 = *(const float4*)(&sm.s[tokl][i * 4]);
            rank += (int)((v4.x > s) || (v4.x == s && (i * 4 + 0) < lane));
            rank += (int)((v4.y > s) || (v4.y == s && (i * 4 + 1) < lane));
            rank += (int)((v4.z > s) || (v4.z == s && (i * 4 + 2) < lane));
            rank += (int)((v4.w > s) || (v4.w == s && (i * 4 + 3) < lane));
        }
        if (rank < TOPK_N + 1) sm.top9[tokl][rank] = s;
        if (rank < TOPK_N)
            out_idx[(size_t)tok * TOPK_N + rank] = (float)lane;
    }
    __syncthreads();

    // tie-screen: TB threads, one per token, scan the 8 gaps of top-9
    if (tid < TB) {
        float ming = 1e30f;
        #pragma unroll
        for (int r = 0; r < TOPK_N; ++r)
            ming = fminf(ming, sm.top9[tid][r] - sm.top9[tid][r + 1]);
        if (ming < TAU) {
            const int sl = atomicAdd(&sm.nflag, 1);
            sm.ftok[sl] = tid;
            sm.fninth[sl] = sm.top9[tid][TOPK_N];   // 9th-best fp32 score
        }
    }
    __syncthreads();

    // inline fp64 recheck of flagged tokens (block-local, rare)
    const int nfl = sm.nflag;
    for (int i = 0; i < nfl; ++i) {
        const int tokl = sm.ftok[i];
        const int tok  = tok0 + tokl;
        const float thr = sm.fninth[i] - TAU;
        const unsigned long long cmask = __ballot(sm.s[tokl][lane] >= thr);
        if (wv == 0) sm.dsc[lane] = -1.0e300;
        __syncthreads();
        // wave wv handles candidate ranks wv, wv+8, ...
        {
            int rank = 0;
            unsigned long long mm = cmask;
            while (mm) {
                const int e = __builtin_ctzll(mm);
                mm &= mm - 1;
                if ((rank & 7) == wv) {
                    const float* wr  = wfp + (size_t)e * DIM;
                    const float* xrr = x + (size_t)tok * DIM;
                    double a = 0.0;
                    #pragma unroll 4
                    for (int kk = 0; kk < 16; ++kk) {
                        const int k = kk * 256 + lane * 4;
                        const float4 wv4 = *(const float4*)(wr + k);
                        const float4 xv  = *(const float4*)(xrr + k);
                        a = fma((double)xv.x, (double)wv4.x, a);
                        a = fma((double)xv.y, (double)wv4.y, a);
                        a = fma((double)xv.z, (double)wv4.z, a);
                        a = fma((double)xv.w, (double)wv4.w, a);
                    }
                    #pragma unroll
                    for (int off = 32; off > 0; off >>= 1)
                        a += __shfl_xor(a, off, 64);
                    if (lane == 0) sm.dsc[e] = a + (double)bias[e];
                }
                ++rank;
            }
        }
        __syncthreads();
        if (wv == 0) {
            double cv = sm.dsc[lane];
            for (int r = 0; r < TOPK_N; ++r) {
                double bv = cv;
                int    bi = lane;
                #pragma unroll
                for (int off = 32; off > 0; off >>= 1) {
                    const double ov = __shfl_xor(bv, off, 64);
                    const int    oi = __shfl_xor(bi, off, 64);
                    if (ov > bv || (ov == bv && oi < bi)) { bv = ov; bi = oi; }
                }
                if (lane == r)
                    out_idx[(size_t)tok * TOPK_N + r] = (float)bi;
                if (lane == bi) cv = -1.0e301;
            }
        }
        __syncthreads();
    }
}

extern "C" void kernel_launch(void* const* d_in, const int* in_sizes, int n_in,
                              void* d_out, int out_size, void* d_ws, size_t ws_size,
                              hipStream_t stream) {
    const float* x  = (const float*)d_in[0];
    const float* w  = (const float*)d_in[1];
    const float* bs = (const float*)d_in[2];
    float* out = (float*)d_out;

    unsigned short* whi = (unsigned short*)((char*)d_ws + WS_WHI_OFF);
    unsigned short* wlo = (unsigned short*)((char*)d_ws + WS_WLO_OFF);

    const int ntok = in_sizes[0] / DIM;          // 8192

    hipLaunchKernelGGL(cvt_w_kernel, dim3((NEXP * DIM) / 8 / 256), dim3(256), 0, stream,
                       w, whi, wlo);
    hipLaunchKernelGGL(gemm_kernel, dim3(ntok / TB), dim3(512), 0, stream,
                       x, whi, wlo, bs, w, out, ntok);
}

// Round 5
// 250.544 us; speedup vs baseline: 1.0505x; 1.0505x over previous
//
#include <hip/hip_runtime.h>
#include <math.h>

#define DIM     4096
#define NEXP    64
#define TOPK_N  8
#define TAU     2.0e-4f
#define TB      32                 // tokens per block
#define BK      128                // k per staged tile
#define KT      (DIM / BK)         // 32 k-steps

#define WS_WHI_OFF  0
#define WS_WLO_OFF  524288

typedef __attribute__((ext_vector_type(8))) short short8;   // 8 bf16
typedef __attribute__((ext_vector_type(4))) float f32x4;

// fp32 -> bf16 hi (trunc) + bf16 lo (trunc of exact residual)
__device__ __forceinline__ void cvt8(float4 a0, float4 a1, short8& hv, short8& lv) {
    float f[8] = {a0.x, a0.y, a0.z, a0.w, a1.x, a1.y, a1.z, a1.w};
    union { short8 v; unsigned u[4]; } H, L;
    #pragma unroll
    for (int i = 0; i < 4; ++i) {
        unsigned b0 = __float_as_uint(f[2*i]);
        unsigned b1 = __float_as_uint(f[2*i+1]);
        float r0 = f[2*i]   - __uint_as_float(b0 & 0xffff0000u);
        float r1 = f[2*i+1] - __uint_as_float(b1 & 0xffff0000u);
        H.u[i] = (b0 >> 16) | (b1 & 0xffff0000u);
        L.u[i] = (__float_as_uint(r0) >> 16) | (__float_as_uint(r1) & 0xffff0000u);
    }
    hv = H.v; lv = L.v;
}

// async global->LDS, 16B per lane; LDS dest = base + lane*16 (linear)
__device__ __forceinline__ void async16(void* lds, const void* g) {
    __builtin_amdgcn_global_load_lds(
        (const __attribute__((address_space(1))) unsigned int*)g,
        (__attribute__((address_space(3))) unsigned int*)lds, 16, 0, 0);
}

// ---------------- Pass 0: w fp32 -> bf16 hi/lo ----------------
__global__ __launch_bounds__(256, 4)
void cvt_w_kernel(const float* __restrict__ w, unsigned short* __restrict__ whi,
                  unsigned short* __restrict__ wlo) {
    const int g = blockIdx.x * 256 + threadIdx.x;
    const float* p = w + (size_t)g * 8;
    union { short8 v; uint4 q; } H, L;
    float4 a0 = *(const float4*)(p);
    float4 a1 = *(const float4*)(p + 4);
    cvt8(a0, a1, H.v, L.v);
    *(uint4*)(whi + (size_t)g * 8) = H.q;
    *(uint4*)(wlo + (size_t)g * 8) = L.q;
}

// Token permutation: block b, local row j -> token ((b*TB+j)*255) & (ntok-1).
// 255 is odd (bijection on 2^13); consecutive local rows map 255 rows (~4MB-16KB)
// apart, so a block's 32 row-streams spread across all HBM channel offsets
// instead of aliasing at 16KB power-of-2 stride. SINGLE variable vs round 3.
#define TOKG(tl) ((((tok0 + (tl)) * 255)) & (ntok - 1))

// ---------------- Pass 1: LDS-staged MFMA bf16x3 GEMM + softmax + top-8 + fp64 recheck ----
// (structure identical to round 3; only the token mapping changed)
__global__ __launch_bounds__(512, 2)
void gemm_kernel(const float* __restrict__ x, const unsigned short* __restrict__ whi,
                 const unsigned short* __restrict__ wlo, const float* __restrict__ bias,
                 const float* __restrict__ wfp, float* __restrict__ out, int ntok) {
    __shared__ struct {
        union {
            struct {
                float          A[2][TB][BK];      // 32 KB (rows 512B, linear)
                unsigned short Bh[2][NEXP][BK];   // 32 KB (rows 256B, linear)
                unsigned short Bl[2][NEXP][BK];   // 32 KB
            } st;
            float part[4][TB][65];                // 33.3 KB (epilogue overlay)
        } u;
        float  s[TB][68];
        float  top9[TB][9];
        double dsc[NEXP];
        int    nflag;
        int    ftok[TB];
        float  fninth[TB];
    } sm;

    const int tid  = threadIdx.x;
    const int lane = tid & 63;
    const int wv   = tid >> 6;
    const int nl   = lane & 15;
    const int q    = lane >> 4;
    const int tok0 = blockIdx.x * TB;
    if (tid == 0) sm.nflag = 0;

    const int ss = wv & 3;          // k-32 substep within BK tile
    const int hf = wv >> 2;         // expert half
    const int abyte = ss * 128 + q * 32;   // byte offset of 8-float group in 512B A row
    const int bbyte = ss * 64 + q * 16;    // byte offset of 8-bf16 group in 256B B row

    // --- per-lane staging constants (swizzled global sources, linear LDS dests) ---
    int arow0[2], be0[2];
    const float* gA[2];
    const unsigned short *gBh[2], *gBl[2];
    #pragma unroll
    for (int i = 0; i < 2; ++i) {
        arow0[i] = wv * 4 + i * 2;                     // A inst covers rows arow0..+1
        const int ra = arow0[i] + (lane >> 5);         // LOCAL row of this lane
        gA[i] = x + (size_t)TOKG(ra) * DIM + (((lane & 31) * 4) ^ ((ra & 7) << 2));
        be0[i] = wv * 8 + i * 4;                       // B inst covers rows be0..+3
        const int ea = be0[i] + (lane >> 4);
        const int el = (((lane & 15) * 8) ^ ((ea & 7) << 3));
        gBh[i] = whi + (size_t)ea * DIM + el;
        gBl[i] = wlo + (size_t)ea * DIM + el;
    }

    f32x4 acc[2][2];
    #pragma unroll
    for (int mg = 0; mg < 2; ++mg)
        #pragma unroll
        for (int nf = 0; nf < 2; ++nf) acc[mg][nf] = (f32x4){0.f, 0.f, 0.f, 0.f};

#define STAGE(b_, k0_) do {                                                    \
        _Pragma("unroll")                                                      \
        for (int i_ = 0; i_ < 2; ++i_) {                                       \
            async16(&sm.u.st.A[b_][arow0[i_]][0],  gA[i_]  + (k0_));           \
            async16(&sm.u.st.Bh[b_][be0[i_]][0],   gBh[i_] + (k0_));           \
            async16(&sm.u.st.Bl[b_][be0[i_]][0],   gBl[i_] + (k0_));           \
        }                                                                      \
    } while (0)

#define COMPUTE(b_) do {                                                       \
        short8 ahi_[2], alo_[2], bh_[2], bl_[2];                               \
        _Pragma("unroll")                                                      \
        for (int mg_ = 0; mg_ < 2; ++mg_) {                                    \
            const int r_ = mg_ * 16 + nl;                                      \
            const char* rp_ = (const char*)&sm.u.st.A[b_][r_][0];              \
            const int sw_ = (r_ & 7) << 4;                                     \
            float4 a0_ = *(const float4*)(rp_ + (abyte ^ sw_));                \
            float4 a1_ = *(const float4*)(rp_ + ((abyte + 16) ^ sw_));         \
            cvt8(a0_, a1_, ahi_[mg_], alo_[mg_]);                              \
        }                                                                      \
        _Pragma("unroll")                                                      \
        for (int nf_ = 0; nf_ < 2; ++nf_) {                                    \
            const int e_ = (hf * 2 + nf_) * 16 + nl;                           \
            const int sw_ = (e_ & 7) << 4;                                     \
            bh_[nf_] = *(const short8*)((const char*)&sm.u.st.Bh[b_][e_][0] + (bbyte ^ sw_)); \
            bl_[nf_] = *(const short8*)((const char*)&sm.u.st.Bl[b_][e_][0] + (bbyte ^ sw_)); \
        }                                                                      \
        _Pragma("unroll")                                                      \
        for (int mg_ = 0; mg_ < 2; ++mg_)                                      \
            _Pragma("unroll")                                                  \
            for (int nf_ = 0; nf_ < 2; ++nf_) {                                \
                acc[mg_][nf_] = __builtin_amdgcn_mfma_f32_16x16x32_bf16(ahi_[mg_], bl_[nf_], acc[mg_][nf_], 0, 0, 0); \
                acc[mg_][nf_] = __builtin_amdgcn_mfma_f32_16x16x32_bf16(alo_[mg_], bh_[nf_], acc[mg_][nf_], 0, 0, 0); \
                acc[mg_][nf_] = __builtin_amdgcn_mfma_f32_16x16x32_bf16(ahi_[mg_], bh_[nf_], acc[mg_][nf_], 0, 0, 0); \
            }                                                                  \
    } while (0)

    // prologue: fill buffer 0
    STAGE(0, 0);
    __syncthreads();
    #pragma unroll 2
    for (int kt = 0; kt < KT; ++kt) {
        const int b = kt & 1;
        if (kt + 1 < KT) STAGE(b ^ 1, (kt + 1) * BK);   // fire-and-forget next tile
        __builtin_amdgcn_sched_barrier(0);              // keep issue before compute
        COMPUTE(b);
        __syncthreads();                                // drains next-tile loads (overlapped)
    }

#undef STAGE
#undef COMPUTE

    // split-K partials -> LDS overlay (safe: barrier above ended all staging reads)
    #pragma unroll
    for (int mg = 0; mg < 2; ++mg)
        #pragma unroll
        for (int nf = 0; nf < 2; ++nf)
            #pragma unroll
            for (int r = 0; r < 4; ++r)
                sm.u.part[ss][mg * 16 + q * 4 + r][(hf * 2 + nf) * 16 + nl] = acc[mg][nf][r];
    __syncthreads();

    // reduce 4 partials (fixed order), add bias: 2048 values / 512 threads
    #pragma unroll
    for (int i = 0; i < (TB * NEXP) / 512; ++i) {
        const int p  = tid + i * 512;
        const int tk = p >> 6, e = p & 63;
        float s = sm.u.part[0][tk][e];
        #pragma unroll
        for (int k = 1; k < 4; ++k) s += sm.u.part[k][tk][e];
        sm.s[tk][e] = s + bias[e];
    }
    __syncthreads();

    // softmax + parallel-rank top-k: wave wv -> tokens wv*4..+4, lane = expert
    float* __restrict__ out_idx = out + (size_t)ntok * NEXP;
    #pragma unroll
    for (int t = 0; t < 4; ++t) {
        const int tokl = wv * 4 + t;
        const int tok  = TOKG(tokl);           // global (permuted) token id
        const float s  = sm.s[tokl][lane];

        float m = s;
        #pragma unroll
        for (int off = 32; off > 0; off >>= 1)
            m = fmaxf(m, __shfl_xor(m, off, 64));
        const float ex = expf(s - m);
        float sum = ex;
        #pragma unroll
        for (int off = 32; off > 0; off >>= 1)
            sum += __shfl_xor(sum, off, 64);
        out[(size_t)tok * NEXP + lane] = ex / sum;

        // rank = #{j : v_j > s || (v_j == s && j < lane)}
        int rank = 0;
        #pragma unroll
        for (int i = 0; i < 16; ++i) {
            const float4 v4 = *(const float4*)(&sm.s[tokl][i * 4]);
            rank += (int)((v4.x > s) || (v4.x == s && (i * 4 + 0) < lane));
            rank += (int)((v4.y > s) || (v4.y == s && (i * 4 + 1) < lane));
            rank += (int)((v4.z > s) || (v4.z == s && (i * 4 + 2) < lane));
            rank += (int)((v4.w > s) || (v4.w == s && (i * 4 + 3) < lane));
        }
        if (rank < TOPK_N + 1) sm.top9[tokl][rank] = s;
        if (rank < TOPK_N)
            out_idx[(size_t)tok * TOPK_N + rank] = (float)lane;
    }
    __syncthreads();

    // tie-screen: TB threads, one per token, scan the 8 gaps of top-9
    if (tid < TB) {
        float ming = 1e30f;
        #pragma unroll
        for (int r = 0; r < TOPK_N; ++r)
            ming = fminf(ming, sm.top9[tid][r] - sm.top9[tid][r + 1]);
        if (ming < TAU) {
            const int sl = atomicAdd(&sm.nflag, 1);
            sm.ftok[sl] = tid;
            sm.fninth[sl] = sm.top9[tid][TOPK_N];   // 9th-best fp32 score
        }
    }
    __syncthreads();

    // inline fp64 recheck of flagged tokens (block-local, rare)
    const int nfl = sm.nflag;
    for (int i = 0; i < nfl; ++i) {
        const int tokl = sm.ftok[i];
        const int tok  = TOKG(tokl);          // global (permuted) token id
        const float thr = sm.fninth[i] - TAU;
        const unsigned long long cmask = __ballot(sm.s[tokl][lane] >= thr);
        if (wv == 0) sm.dsc[lane] = -1.0e300;
        __syncthreads();
        // wave wv handles candidate ranks wv, wv+8, ...
        {
            int rank = 0;
            unsigned long long mm = cmask;
            while (mm) {
                const int e = __builtin_ctzll(mm);
                mm &= mm - 1;
                if ((rank & 7) == wv) {
                    const float* wr  = wfp + (size_t)e * DIM;
                    const float* xrr = x + (size_t)tok * DIM;
                    double a = 0.0;
                    #pragma unroll 4
                    for (int kk = 0; kk < 16; ++kk) {
                        const int k = kk * 256 + lane * 4;
                        const float4 wv4 = *(const float4*)(wr + k);
                        const float4 xv  = *(const float4*)(xrr + k);
                        a = fma((double)xv.x, (double)wv4.x, a);
                        a = fma((double)xv.y, (double)wv4.y, a);
                        a = fma((double)xv.z, (double)wv4.z, a);
                        a = fma((double)xv.w, (double)wv4.w, a);
                    }
                    #pragma unroll
                    for (int off = 32; off > 0; off >>= 1)
                        a += __shfl_xor(a, off, 64);
                    if (lane == 0) sm.dsc[e] = a + (double)bias[e];
                }
                ++rank;
            }
        }
        __syncthreads();
        if (wv == 0) {
            double cv = sm.dsc[lane];
            for (int r = 0; r < TOPK_N; ++r) {
                double bv = cv;
                int    bi = lane;
                #pragma unroll
                for (int off = 32; off > 0; off >>= 1) {
                    const double ov = __shfl_xor(bv, off, 64);
                    const int    oi = __shfl_xor(bi, off, 64);
                    if (ov > bv || (ov == bv && oi < bi)) { bv = ov; bi = oi; }
                }
                if (lane == r)
                    out_idx[(size_t)tok * TOPK_N + r] = (float)bi;
                if (lane == bi) cv = -1.0e301;
            }
        }
        __syncthreads();
    }
}

extern "C" void kernel_launch(void* const* d_in, const int* in_sizes, int n_in,
                              void* d_out, int out_size, void* d_ws, size_t ws_size,
                              hipStream_t stream) {
    const float* x  = (const float*)d_in[0];
    const float* w  = (const float*)d_in[1];
    const float* bs = (const float*)d_in[2];
    float* out = (float*)d_out;

    unsigned short* whi = (unsigned short*)((char*)d_ws + WS_WHI_OFF);
    unsigned short* wlo = (unsigned short*)((char*)d_ws + WS_WLO_OFF);

    const int ntok = in_sizes[0] / DIM;          // 8192

    hipLaunchKernelGGL(cvt_w_kernel, dim3((NEXP * DIM) / 8 / 256), dim3(256), 0, stream,
                       w, whi, wlo);
    hipLaunchKernelGGL(gemm_kernel, dim3(ntok / TB), dim3(512), 0, stream,
                       x, whi, wlo, bs, w, out, ntok);
}